// Round 11
// baseline (129.112 us; speedup 1.0000x reference)
//
#include <hip/hip_runtime.h>
#include <stdint.h>

#define BB 128
#define SS 4096
#define DD 64
#define HH 256

typedef short bf16x8 __attribute__((ext_vector_type(8)));
typedef float f32x16 __attribute__((ext_vector_type(16)));

__device__ __forceinline__ uint32_t cvt_pk_bf16(float lo, float hi) {
  uint32_t r;
  asm("v_cvt_pk_bf16_f32 %0, %1, %2" : "=v"(r) : "v"(lo), "v"(hi));
  return r;
}

// v_permlane32_swap_b32: new_a = [a.row0, b.row0], new_b = [a.row1, b.row1]
__device__ __forceinline__ void permswap(uint32_t& a, uint32_t& b) {
  asm("v_permlane32_swap_b32 %0, %1" : "+v"(a), "+v"(b));
}

// minimal silu: 1 mul + v_exp_f32 + 1 add + v_rcp + 1 mul
__device__ __forceinline__ float silu_f(float v) {
  float e;
  asm("v_exp_f32 %0, %1" : "=v"(e) : "v"(v * -1.44269504f));
  return v * __builtin_amdgcn_rcpf(1.0f + e);
}

__device__ __forceinline__ void gload16(const void* g, void* l) {
  __builtin_amdgcn_global_load_lds(
      (const __attribute__((address_space(1))) void*)g,
      (__attribute__((address_space(3))) void*)l, 16, 0, 0);
}

// -------- pre-pass: weights -> FRAGMENT-MAJOR bf16 layout in workspace -----
// W1f: per b, 32 tiles (hc*4+kc) of 64 lanes x 16B:
//   lane holds W1[d = kc*16+(lane>>5)*8 + j][h = hc*32+(lane&31)], j=0..7
// W2f: per b, 32 tiles (hc*4+mt*2+c) of 64 lanes x 16B:
//   lane holds W2[h = hc*32+c*16+(lane>>5)*8 + j][d = mt*32+(lane&31)]
__global__ __launch_bounds__(256) void transpose_w(
    const float* __restrict__ W1, const float* __restrict__ W2,
    ushort* __restrict__ W1f, ushort* __restrict__ W2f) {
  int g = blockIdx.x * 256 + threadIdx.x;
  const int half = (BB * DD * HH) / 8;  // 262144
  float v[8];
  if (g < half) {
    size_t e = (size_t)g * 8;            // ushort index: b|tile|lane|j
    int b = (int)(e >> 14);
    int rem = (int)(e & 16383);
    int tile = rem >> 9;                 // hc*4 + kc
    int lane6 = (rem >> 3) & 63;
    int hc = tile >> 2, kc = tile & 3;
    int h = hc * 32 + (lane6 & 31);
    int d0 = kc * 16 + (lane6 >> 5) * 8;
    const float* src = W1 + ((size_t)b << 14) + h;  // + d*256
#pragma unroll
    for (int j = 0; j < 8; ++j) v[j] = src[(size_t)(d0 + j) << 8];
    uint4 o;
    o.x = cvt_pk_bf16(v[0], v[1]); o.y = cvt_pk_bf16(v[2], v[3]);
    o.z = cvt_pk_bf16(v[4], v[5]); o.w = cvt_pk_bf16(v[6], v[7]);
    *reinterpret_cast<uint4*>(W1f + e) = o;
  } else if (g < 2 * half) {
    size_t e = (size_t)(g - half) * 8;
    int b = (int)(e >> 14);
    int rem = (int)(e & 16383);
    int tile = rem >> 9;                 // hc*4 + mt*2 + c
    int lane6 = (rem >> 3) & 63;
    int hc = tile >> 2, mt = (tile >> 1) & 1, c = tile & 1;
    int d = mt * 32 + (lane6 & 31);
    int h0 = hc * 32 + c * 16 + (lane6 >> 5) * 8;
    const float* src = W2 + ((size_t)b << 14) + d;  // + h*64
#pragma unroll
    for (int j = 0; j < 8; ++j) v[j] = src[(size_t)(h0 + j) << 6];
    uint4 o;
    o.x = cvt_pk_bf16(v[0], v[1]); o.y = cvt_pk_bf16(v[2], v[3]);
    o.z = cvt_pk_bf16(v[4], v[5]); o.w = cvt_pk_bf16(v[6], v[7]);
    *reinterpret_cast<uint4*>(W2f + e) = o;
  }
}

// ---------------- main fused kernel: producer/consumer waves ----------------
// Block = 512 thr (8 waves), one b, 256 s-rows. Waves 0-3 = PRODUCERS (64
// s-rows each): GEMM1 + silu + pack -> bf16 h-fragments into LDS (double-
// buffered). Waves 4-7 = CONSUMERS (same 64 rows): read h-frags + GEMM2 +
// residual + store. Each SIMD hosts 1 producer (trans/VALU-heavy) + 1
// consumer (MFMA-heavy) -> pipe overlap by construction. 9-iteration
// uniform barrier loop: produce(k) || consume(k-1).
// LDS 96 KB: W1f [0,32K) | W2f [32K,64K) | hbuf 2x16KB [64K,96K).
__global__ __launch_bounds__(512, 2) void mlp_fused(
    const float* __restrict__ xg, const ushort* __restrict__ w1f,
    const ushort* __restrict__ w2f, float* __restrict__ outg) {
  __shared__ int4 lds4[98304 / 16];
  char* lds = (char*)lds4;
  char* ldsW1 = lds;
  char* ldsW2 = lds + 32768;
  char* hbuf = lds + 65536;

  const int tid = threadIdx.x;
  const int wave = tid >> 6;
  const int lane = tid & 63;
  const int l31 = lane & 31;
  const int g5 = lane >> 5;
  const bool producer = wave < 4;
  const int p = producer ? wave : wave - 4;  // tile index 0..3

  // 2048 blocks; XCD-aware swizzle: XCD k owns b in [16k, 16k+16)
  int raw = blockIdx.x;
  int logical = (raw & 7) * 256 + (raw >> 3);
  const int b = logical >> 4;            // 16 blocks per b
  const int st = logical & 15;
  const int s_wave = st * 256 + p * 64;  // this wave-pair's 64 rows

  const float* xb = xg + (((size_t)b * SS + s_wave) << 6);
  const char* w1b = (const char*)(w1f + ((size_t)b << 14));
  const char* w2b = (const char*)(w2f + ((size_t)b << 14));

  // ---- staging: producers stage W1f, consumers stage W2f (32 KB each) ----
  {
    int t = producer ? tid : tid - 256;  // 0..255
#pragma unroll
    for (int r = 0; r < 8; ++r) {
      uint32_t o = (uint32_t)(r * 4096 + t * 16);
      if (producer) gload16(w1b + o, ldsW1 + o);
      else          gload16(w2b + o, ldsW2 + o);
    }
  }

  // ---- per-role register state (x reads overlap staging latency) ----
  bf16x8 bx[2][4];   // producer: x B-frags, rows 32nt+l31
  f32x16 acc[2][2];  // consumer: acc[nt][mt], residual-initialized
  if (producer) {
#pragma unroll
    for (int nt = 0; nt < 2; ++nt)
#pragma unroll
      for (int kc = 0; kc < 4; ++kc) {
        const float* q = xb + ((size_t)(nt * 32 + l31) << 6) + kc * 16 + g5 * 8;
        float4 fa = *reinterpret_cast<const float4*>(q);
        float4 fb = *reinterpret_cast<const float4*>(q + 4);
        union { uint32_t u[4]; bf16x8 v; } cv;
        cv.u[0] = cvt_pk_bf16(fa.x, fa.y);
        cv.u[1] = cvt_pk_bf16(fa.z, fa.w);
        cv.u[2] = cvt_pk_bf16(fb.x, fb.y);
        cv.u[3] = cvt_pk_bf16(fb.z, fb.w);
        bx[nt][kc] = cv.v;
      }
  } else {
#pragma unroll
    for (int nt = 0; nt < 2; ++nt) {
      const float* prow = xb + ((size_t)(nt * 32 + l31) << 6);
#pragma unroll
      for (int mt = 0; mt < 2; ++mt)
#pragma unroll
        for (int q = 0; q < 4; ++q) {
          float4 v = *reinterpret_cast<const float4*>(prow + mt * 32 + q * 8 +
                                                      g5 * 4);
          acc[nt][mt][4 * q + 0] = v.x;
          acc[nt][mt][4 * q + 1] = v.y;
          acc[nt][mt][4 * q + 2] = v.z;
          acc[nt][mt][4 * q + 3] = v.w;
        }
    }
  }

  __syncthreads();  // staging complete

  const char* lw1 = ldsW1 + lane * 16;
  const char* lw2 = ldsW2 + lane * 16;
  char* hme = hbuf + p * 4096 + lane * 16;  // this pair's frag slot

  const f32x16 vzero = {0.f, 0.f, 0.f, 0.f, 0.f, 0.f, 0.f, 0.f,
                        0.f, 0.f, 0.f, 0.f, 0.f, 0.f, 0.f, 0.f};

#pragma unroll
  for (int k = 0; k < 9; ++k) {
    if (producer && k < 8) {
      // ---- GEMM1 (swapped): shared a1 frags, two s-subtiles ----
      bf16x8 a1[4];
#pragma unroll
      for (int kc = 0; kc < 4; ++kc)
        a1[kc] = *reinterpret_cast<const bf16x8*>(lw1 + (k * 4 + kc) * 1024);
      f32x16 ah[2];
      ah[0] = vzero; ah[1] = vzero;
#pragma unroll
      for (int kc = 0; kc < 4; ++kc) {
        ah[0] = __builtin_amdgcn_mfma_f32_32x32x16_bf16(a1[kc], bx[0][kc],
                                                        ah[0], 0, 0, 0);
        ah[1] = __builtin_amdgcn_mfma_f32_32x32x16_bf16(a1[kc], bx[1][kc],
                                                        ah[1], 0, 0, 0);
      }
      // ---- silu + pack + permswap -> bh frags -> LDS (bh-format) ----
#pragma unroll
      for (int nt = 0; nt < 2; ++nt) {
#pragma unroll
        for (int c = 0; c < 2; ++c) {
          uint32_t A0 = cvt_pk_bf16(silu_f(ah[nt][8 * c + 0]),
                                    silu_f(ah[nt][8 * c + 1]));
          uint32_t A1 = cvt_pk_bf16(silu_f(ah[nt][8 * c + 2]),
                                    silu_f(ah[nt][8 * c + 3]));
          uint32_t B0 = cvt_pk_bf16(silu_f(ah[nt][8 * c + 4]),
                                    silu_f(ah[nt][8 * c + 5]));
          uint32_t B1 = cvt_pk_bf16(silu_f(ah[nt][8 * c + 6]),
                                    silu_f(ah[nt][8 * c + 7]));
          permswap(A0, B0);
          permswap(A1, B1);
          union { uint32_t u[4]; bf16x8 v; } f;
          f.u[0] = A0; f.u[1] = A1; f.u[2] = B0; f.u[3] = B1;
          *reinterpret_cast<bf16x8*>(hme + (k & 1) * 16384 + nt * 2048 +
                                     c * 1024) = f.v;
        }
      }
    } else if (!producer && k > 0) {
      const int kk = k - 1;
      // ---- GEMM2 (swapped): h-frags + a2 frags from LDS ----
      bf16x8 bh[2][2];
#pragma unroll
      for (int nt = 0; nt < 2; ++nt)
#pragma unroll
        for (int c = 0; c < 2; ++c)
          bh[nt][c] = *reinterpret_cast<const bf16x8*>(
              hme + (kk & 1) * 16384 + nt * 2048 + c * 1024);
      bf16x8 a2[2][2];
#pragma unroll
      for (int mt = 0; mt < 2; ++mt)
#pragma unroll
        for (int c = 0; c < 2; ++c)
          a2[mt][c] = *reinterpret_cast<const bf16x8*>(
              lw2 + (kk * 4 + mt * 2 + c) * 1024);
#pragma unroll
      for (int c = 0; c < 2; ++c)
#pragma unroll
        for (int nt = 0; nt < 2; ++nt)
#pragma unroll
          for (int mt = 0; mt < 2; ++mt)
            acc[nt][mt] = __builtin_amdgcn_mfma_f32_32x32x16_bf16(
                a2[mt][c], bh[nt][c], acc[nt][mt], 0, 0, 0);
    }
    __syncthreads();
  }

  // ---- epilogue: consumers store out = acc (residual already in) ----
  if (!producer) {
#pragma unroll
    for (int nt = 0; nt < 2; ++nt) {
      float* prow = outg + (((size_t)b * SS + s_wave + nt * 32 + l31) << 6);
#pragma unroll
      for (int mt = 0; mt < 2; ++mt)
#pragma unroll
        for (int q = 0; q < 4; ++q) {
          float4 v;
          v.x = acc[nt][mt][4 * q + 0];
          v.y = acc[nt][mt][4 * q + 1];
          v.z = acc[nt][mt][4 * q + 2];
          v.w = acc[nt][mt][4 * q + 3];
          *reinterpret_cast<float4*>(prow + mt * 32 + q * 8 + g5 * 4) = v;
        }
    }
  }
}

extern "C" void kernel_launch(void* const* d_in, const int* in_sizes, int n_in,
                              void* d_out, int out_size, void* d_ws, size_t ws_size,
                              hipStream_t stream) {
  const float* x  = (const float*)d_in[0];
  const float* W1 = (const float*)d_in[1];
  const float* W2 = (const float*)d_in[2];
  float* out = (float*)d_out;

  ushort* W1f = (ushort*)d_ws;                       // bf16 frag-major, 4 MB
  ushort* W2f = W1f + (size_t)BB * DD * HH;          // bf16 frag-major, 4 MB

  transpose_w<<<2048, 256, 0, stream>>>(W1, W2, W1f, W2f);
  mlp_fused<<<2048, 512, 0, stream>>>(x, W1f, W2f, out);
}

// Round 12
// 85.511 us; speedup vs baseline: 1.5099x; 1.5099x over previous
//
#include <hip/hip_runtime.h>
#include <stdint.h>

#define BB 128
#define SS 4096
#define DD 64
#define HH 256

typedef short bf16x8 __attribute__((ext_vector_type(8)));
typedef float f32x16 __attribute__((ext_vector_type(16)));
typedef float f32x2 __attribute__((ext_vector_type(2)));

__device__ __forceinline__ uint32_t cvt_pk_bf16(float lo, float hi) {
  uint32_t r;
  asm("v_cvt_pk_bf16_f32 %0, %1, %2" : "=v"(r) : "v"(lo), "v"(hi));
  return r;
}

// v_permlane32_swap_b32: new_a = [a.row0, b.row0], new_b = [a.row1, b.row1]
__device__ __forceinline__ void permswap(uint32_t& a, uint32_t& b) {
  asm("v_permlane32_swap_b32 %0, %1" : "+v"(a), "+v"(b));
}

// packed-f32 silu on a pair, returns packed bf16 word.
// v_pk_mul_f32 / v_pk_add_f32 halve VALU issue; exp/rcp stay scalar trans.
__device__ __forceinline__ uint32_t silu2_pack(float a, float b) {
  f32x2 v = {a, b};
  f32x2 m = v * (-1.44269504f);          // v_pk_mul_f32
  float ea, eb;
  asm("v_exp_f32 %0, %1" : "=v"(ea) : "v"(m.x));
  asm("v_exp_f32 %0, %1" : "=v"(eb) : "v"(m.y));
  f32x2 d = {ea, eb};
  d = d + (f32x2){1.0f, 1.0f};           // v_pk_add_f32
  f32x2 r = {__builtin_amdgcn_rcpf(d.x), __builtin_amdgcn_rcpf(d.y)};
  f32x2 o = v * r;                       // v_pk_mul_f32
  return cvt_pk_bf16(o.x, o.y);
}

__device__ __forceinline__ void gload16(const void* g, void* l) {
  __builtin_amdgcn_global_load_lds(
      (const __attribute__((address_space(1))) void*)g,
      (__attribute__((address_space(3))) void*)l, 16, 0, 0);
}

// -------- pre-pass: weights -> FRAGMENT-MAJOR bf16 layout in workspace -----
// W1f: per b, 32 tiles (hc*4+kc) of 64 lanes x 16B:
//   lane holds W1[d = kc*16+(lane>>5)*8 + j][h = hc*32+(lane&31)], j=0..7
// W2f: per b, 32 tiles (hc*4+mt*2+c) of 64 lanes x 16B:
//   lane holds W2[h = hc*32+c*16+(lane>>5)*8 + j][d = mt*32+(lane&31)]
__global__ __launch_bounds__(256) void transpose_w(
    const float* __restrict__ W1, const float* __restrict__ W2,
    ushort* __restrict__ W1f, ushort* __restrict__ W2f) {
  int g = blockIdx.x * 256 + threadIdx.x;
  const int half = (BB * DD * HH) / 8;  // 262144
  float v[8];
  if (g < half) {
    size_t e = (size_t)g * 8;            // ushort index: b|tile|lane|j
    int b = (int)(e >> 14);
    int rem = (int)(e & 16383);
    int tile = rem >> 9;                 // hc*4 + kc
    int lane6 = (rem >> 3) & 63;
    int hc = tile >> 2, kc = tile & 3;
    int h = hc * 32 + (lane6 & 31);
    int d0 = kc * 16 + (lane6 >> 5) * 8;
    const float* src = W1 + ((size_t)b << 14) + h;  // + d*256
#pragma unroll
    for (int j = 0; j < 8; ++j) v[j] = src[(size_t)(d0 + j) << 8];
    uint4 o;
    o.x = cvt_pk_bf16(v[0], v[1]); o.y = cvt_pk_bf16(v[2], v[3]);
    o.z = cvt_pk_bf16(v[4], v[5]); o.w = cvt_pk_bf16(v[6], v[7]);
    *reinterpret_cast<uint4*>(W1f + e) = o;
  } else if (g < 2 * half) {
    size_t e = (size_t)(g - half) * 8;
    int b = (int)(e >> 14);
    int rem = (int)(e & 16383);
    int tile = rem >> 9;                 // hc*4 + mt*2 + c
    int lane6 = (rem >> 3) & 63;
    int hc = tile >> 2, mt = (tile >> 1) & 1, c = tile & 1;
    int d = mt * 32 + (lane6 & 31);
    int h0 = hc * 32 + c * 16 + (lane6 >> 5) * 8;
    const float* src = W2 + ((size_t)b << 14) + d;  // + h*64
#pragma unroll
    for (int j = 0; j < 8; ++j) v[j] = src[(size_t)(h0 + j) << 6];
    uint4 o;
    o.x = cvt_pk_bf16(v[0], v[1]); o.y = cvt_pk_bf16(v[2], v[3]);
    o.z = cvt_pk_bf16(v[4], v[5]); o.w = cvt_pk_bf16(v[6], v[7]);
    *reinterpret_cast<uint4*>(W2f + e) = o;
  }
}

// ---------------- main fused kernel ----------------
// Block = 512 thr (8 waves), one b, 256 s-rows (wave = 32 rows).
// LDS 64 KB fragment-major: W1f tiles [0,32K), W2f tiles [32K,64K).
// All LDS reads: ds_read_b128 at lane*16 + literal offset (0 addr math,
// 0 conflicts). h in 8 chunks of 32.
// launch_bounds(512,4): ~128 unified regs -> compiler can hoist/pipeline
// (r7/r8's 5-wave bound starved it to 52 regs and serialized the chain);
// 4 waves/SIMD aligns with the 64KB-LDS cap of 16 waves/CU.
__global__ __launch_bounds__(512, 4) void mlp_fused(
    const float* __restrict__ xg, const ushort* __restrict__ w1f,
    const ushort* __restrict__ w2f, float* __restrict__ outg) {
  __shared__ int4 lds4[65536 / 16];
  char* lds = (char*)lds4;

  const int tid = threadIdx.x;
  const int wave = tid >> 6;
  const int lane = tid & 63;
  const int l31 = lane & 31;
  const int g5 = lane >> 5;

  // 2048 blocks; XCD-aware swizzle: XCD k owns b in [16k, 16k+16)
  int raw = blockIdx.x;
  int logical = (raw & 7) * 256 + (raw >> 3);
  const int b = logical >> 4;            // 16 blocks per b
  const int st = logical & 15;
  const int s_base = st * 256 + wave * 32;

  const float* xb = xg + (((size_t)b * SS + s_base) << 6);
  const char* w1b = (const char*)(w1f + ((size_t)b << 14));
  const char* w2b = (const char*)(w2f + ((size_t)b << 14));

  // stage weights: pure linear copy (fragment-major already)
#pragma unroll
  for (int r = 0; r < 4; ++r) {
    uint32_t o = (uint32_t)(r * 8192 + tid * 16);
    gload16(w1b + o, lds + o);
    gload16(w2b + o, lds + 32768 + o);
  }

  // x B-frags for GEMM1 (f32 -> bf16): lane = x[s=l31][d=16kc+8g5..+7]
  bf16x8 bx[4];
#pragma unroll
  for (int kc = 0; kc < 4; ++kc) {
    const float* p = xb + ((size_t)l31 << 6) + kc * 16 + g5 * 8;
    float4 fa = *reinterpret_cast<const float4*>(p);
    float4 fb = *reinterpret_cast<const float4*>(p + 4);
    union { uint32_t u[4]; bf16x8 v; } cv;
    cv.u[0] = cvt_pk_bf16(fa.x, fa.y);
    cv.u[1] = cvt_pk_bf16(fa.z, fa.w);
    cv.u[2] = cvt_pk_bf16(fb.x, fb.y);
    cv.u[3] = cvt_pk_bf16(fb.z, fb.w);
    bx[kc] = cv.v;
  }

  // acc init = residual x (f32-exact): acc[mt][4q+j] = x[s=l31][d=32mt+8q+4g5+j]
  f32x16 acc[2];
  {
    const float* prow = xb + ((size_t)l31 << 6);
#pragma unroll
    for (int mt = 0; mt < 2; ++mt)
#pragma unroll
      for (int q = 0; q < 4; ++q) {
        float4 v =
            *reinterpret_cast<const float4*>(prow + mt * 32 + q * 8 + g5 * 4);
        acc[mt][4 * q + 0] = v.x;
        acc[mt][4 * q + 1] = v.y;
        acc[mt][4 * q + 2] = v.z;
        acc[mt][4 * q + 3] = v.w;
      }
  }

  __syncthreads();  // weight staging complete

  const char* lw1 = lds + lane * 16;
  const char* lw2 = lds + 32768 + lane * 16;

  const f32x16 vzero = {0.f, 0.f, 0.f, 0.f, 0.f, 0.f, 0.f, 0.f,
                        0.f, 0.f, 0.f, 0.f, 0.f, 0.f, 0.f, 0.f};

#pragma unroll
  for (int hc = 0; hc < 8; ++hc) {
    // ---- GEMM1 (swapped, 32h x 32s): two parallel dep-chains ----
    bf16x8 a1[4];
#pragma unroll
    for (int kc = 0; kc < 4; ++kc)
      a1[kc] = *reinterpret_cast<const bf16x8*>(lw1 + (hc * 4 + kc) * 1024);
    f32x16 ah0 = vzero, ah1 = vzero;
    ah0 = __builtin_amdgcn_mfma_f32_32x32x16_bf16(a1[0], bx[0], ah0, 0, 0, 0);
    ah1 = __builtin_amdgcn_mfma_f32_32x32x16_bf16(a1[1], bx[1], ah1, 0, 0, 0);
    ah0 = __builtin_amdgcn_mfma_f32_32x32x16_bf16(a1[2], bx[2], ah0, 0, 0, 0);
    ah1 = __builtin_amdgcn_mfma_f32_32x32x16_bf16(a1[3], bx[3], ah1, 0, 0, 0);
    f32x16 ah = ah0 + ah1;  // v_pk_add_f32 x8

    // ---- silu (packed f32) + pack + permlane32_swap -> GEMM2 B-frags ----
    // ah idx=4q+j holds h_in_chunk = 8q+4g5+j (s = l31).
    // bh[c] word w: k_in_chunk = 16c + 8g5 + 2w + {0,1}.
    bf16x8 bh[2];
#pragma unroll
    for (int c = 0; c < 2; ++c) {
      uint32_t A0 = silu2_pack(ah[8 * c + 0], ah[8 * c + 1]);
      uint32_t A1 = silu2_pack(ah[8 * c + 2], ah[8 * c + 3]);
      uint32_t B0 = silu2_pack(ah[8 * c + 4], ah[8 * c + 5]);
      uint32_t B1 = silu2_pack(ah[8 * c + 6], ah[8 * c + 7]);
      permswap(A0, B0);
      permswap(A1, B1);
      union { uint32_t u[4]; bf16x8 v; } f;
      f.u[0] = A0; f.u[1] = A1; f.u[2] = B0; f.u[3] = B1;
      bh[c] = f.v;
    }

    // ---- GEMM2 (swapped): out^T += W2f[:, chunk] * h^T ----
#pragma unroll
    for (int c = 0; c < 2; ++c)
#pragma unroll
      for (int mt = 0; mt < 2; ++mt) {
        bf16x8 a2 = *reinterpret_cast<const bf16x8*>(
            lw2 + (hc * 4 + mt * 2 + c) * 1024);
        acc[mt] =
            __builtin_amdgcn_mfma_f32_32x32x16_bf16(a2, bh[c], acc[mt], 0, 0, 0);
      }
  }

  // ---- epilogue: direct global stores ----
  float* prow = outg + (((size_t)b * SS + s_base + l31) << 6);
#pragma unroll
  for (int mt = 0; mt < 2; ++mt)
#pragma unroll
    for (int q = 0; q < 4; ++q) {
      float4 v;
      v.x = acc[mt][4 * q + 0];
      v.y = acc[mt][4 * q + 1];
      v.z = acc[mt][4 * q + 2];
      v.w = acc[mt][4 * q + 3];
      *reinterpret_cast<float4*>(prow + mt * 32 + q * 8 + g5 * 4) = v;
    }
}

extern "C" void kernel_launch(void* const* d_in, const int* in_sizes, int n_in,
                              void* d_out, int out_size, void* d_ws, size_t ws_size,
                              hipStream_t stream) {
  const float* x  = (const float*)d_in[0];
  const float* W1 = (const float*)d_in[1];
  const float* W2 = (const float*)d_in[2];
  float* out = (float*)d_out;

  ushort* W1f = (ushort*)d_ws;                       // bf16 frag-major, 4 MB
  ushort* W2f = W1f + (size_t)BB * DD * HH;          // bf16 frag-major, 4 MB

  transpose_w<<<2048, 256, 0, stream>>>(W1, W2, W1f, W2f);
  mlp_fused<<<2048, 512, 0, stream>>>(x, W1f, W2f, out);
}

// Round 13
// 85.017 us; speedup vs baseline: 1.5187x; 1.0058x over previous
//
#include <hip/hip_runtime.h>
#include <stdint.h>

#define BB 128
#define SS 4096
#define DD 64
#define HH 256

typedef short bf16x8 __attribute__((ext_vector_type(8)));
typedef float f32x16 __attribute__((ext_vector_type(16)));
typedef float f32x2 __attribute__((ext_vector_type(2)));

__device__ __forceinline__ uint32_t cvt_pk_bf16(float lo, float hi) {
  uint32_t r;
  asm("v_cvt_pk_bf16_f32 %0, %1, %2" : "=v"(r) : "v"(lo), "v"(hi));
  return r;
}

// v_permlane32_swap_b32: new_a = [a.row0, b.row0], new_b = [a.row1, b.row1]
__device__ __forceinline__ void permswap(uint32_t& a, uint32_t& b) {
  asm("v_permlane32_swap_b32 %0, %1" : "+v"(a), "+v"(b));
}

// packed-f32 silu on a pair, returns packed bf16 word.
__device__ __forceinline__ uint32_t silu2_pack(float a, float b) {
  f32x2 v = {a, b};
  f32x2 m = v * (-1.44269504f);          // v_pk_mul_f32
  float ea, eb;
  asm("v_exp_f32 %0, %1" : "=v"(ea) : "v"(m.x));
  asm("v_exp_f32 %0, %1" : "=v"(eb) : "v"(m.y));
  f32x2 d = {ea, eb};
  d = d + (f32x2){1.0f, 1.0f};           // v_pk_add_f32
  f32x2 r = {__builtin_amdgcn_rcpf(d.x), __builtin_amdgcn_rcpf(d.y)};
  f32x2 o = v * r;                       // v_pk_mul_f32
  return cvt_pk_bf16(o.x, o.y);
}

__device__ __forceinline__ void gload16(const void* g, void* l) {
  __builtin_amdgcn_global_load_lds(
      (const __attribute__((address_space(1))) void*)g,
      (__attribute__((address_space(3))) void*)l, 16, 0, 0);
}

// -------- pre-pass: weights -> FRAGMENT-MAJOR bf16 layout in workspace -----
// W1f: per b, 32 tiles (hc*4+kc) of 64 lanes x 16B:
//   lane holds W1[d = kc*16+(lane>>5)*8 + j][h = hc*32+(lane&31)], j=0..7
// W2f: per b, 32 tiles (hc*4+mt*2+c) of 64 lanes x 16B:
//   lane holds W2[h = hc*32+c*16+(lane>>5)*8 + j][d = mt*32+(lane&31)]
__global__ __launch_bounds__(256) void transpose_w(
    const float* __restrict__ W1, const float* __restrict__ W2,
    ushort* __restrict__ W1f, ushort* __restrict__ W2f) {
  int g = blockIdx.x * 256 + threadIdx.x;
  const int half = (BB * DD * HH) / 8;  // 262144
  float v[8];
  if (g < half) {
    size_t e = (size_t)g * 8;            // ushort index: b|tile|lane|j
    int b = (int)(e >> 14);
    int rem = (int)(e & 16383);
    int tile = rem >> 9;                 // hc*4 + kc
    int lane6 = (rem >> 3) & 63;
    int hc = tile >> 2, kc = tile & 3;
    int h = hc * 32 + (lane6 & 31);
    int d0 = kc * 16 + (lane6 >> 5) * 8;
    const float* src = W1 + ((size_t)b << 14) + h;  // + d*256
#pragma unroll
    for (int j = 0; j < 8; ++j) v[j] = src[(size_t)(d0 + j) << 8];
    uint4 o;
    o.x = cvt_pk_bf16(v[0], v[1]); o.y = cvt_pk_bf16(v[2], v[3]);
    o.z = cvt_pk_bf16(v[4], v[5]); o.w = cvt_pk_bf16(v[6], v[7]);
    *reinterpret_cast<uint4*>(W1f + e) = o;
  } else if (g < 2 * half) {
    size_t e = (size_t)(g - half) * 8;
    int b = (int)(e >> 14);
    int rem = (int)(e & 16383);
    int tile = rem >> 9;                 // hc*4 + mt*2 + c
    int lane6 = (rem >> 3) & 63;
    int hc = tile >> 2, mt = (tile >> 1) & 1, c = tile & 1;
    int d = mt * 32 + (lane6 & 31);
    int h0 = hc * 32 + c * 16 + (lane6 >> 5) * 8;
    const float* src = W2 + ((size_t)b << 14) + d;  // + h*64
#pragma unroll
    for (int j = 0; j < 8; ++j) v[j] = src[(size_t)(h0 + j) << 6];
    uint4 o;
    o.x = cvt_pk_bf16(v[0], v[1]); o.y = cvt_pk_bf16(v[2], v[3]);
    o.z = cvt_pk_bf16(v[4], v[5]); o.w = cvt_pk_bf16(v[6], v[7]);
    *reinterpret_cast<uint4*>(W2f + e) = o;
  }
}

// ---------------- main fused kernel ----------------
// Block = 512 thr (8 waves), one b, 256 s-rows (wave = 32 rows).
// LDS 64 KB fragment-major: W1f [0,32K), W2f [32K,64K); all reads are
// ds_read_b128 at lane*16 + literal offset (0 addr math, 0 conflicts).
// h in 4 PAIRS of 32-chunks: two independent GEMM1/silu/GEMM2 streams per
// pair, written so both ah live ranges overlap -> regalloc CANNOT collapse
// to the 52-reg serial schedule (r12's tell). silu(A) hides under GEMM(B).
__global__ __launch_bounds__(512, 3) void mlp_fused(
    const float* __restrict__ xg, const ushort* __restrict__ w1f,
    const ushort* __restrict__ w2f, float* __restrict__ outg) {
  __shared__ int4 lds4[65536 / 16];
  char* lds = (char*)lds4;

  const int tid = threadIdx.x;
  const int wave = tid >> 6;
  const int lane = tid & 63;
  const int l31 = lane & 31;
  const int g5 = lane >> 5;

  // 2048 blocks; XCD-aware swizzle: XCD k owns b in [16k, 16k+16)
  int raw = blockIdx.x;
  int logical = (raw & 7) * 256 + (raw >> 3);
  const int b = logical >> 4;            // 16 blocks per b
  const int st = logical & 15;
  const int s_base = st * 256 + wave * 32;

  const float* xb = xg + (((size_t)b * SS + s_base) << 6);
  const char* w1b = (const char*)(w1f + ((size_t)b << 14));
  const char* w2b = (const char*)(w2f + ((size_t)b << 14));

  // stage weights: pure linear copy (fragment-major already)
#pragma unroll
  for (int r = 0; r < 4; ++r) {
    uint32_t o = (uint32_t)(r * 8192 + tid * 16);
    gload16(w1b + o, lds + o);
    gload16(w2b + o, lds + 32768 + o);
  }

  // x B-frags for GEMM1 (f32 -> bf16): lane = x[s=l31][d=16kc+8g5..+7]
  bf16x8 bx[4];
#pragma unroll
  for (int kc = 0; kc < 4; ++kc) {
    const float* p = xb + ((size_t)l31 << 6) + kc * 16 + g5 * 8;
    float4 fa = *reinterpret_cast<const float4*>(p);
    float4 fb = *reinterpret_cast<const float4*>(p + 4);
    union { uint32_t u[4]; bf16x8 v; } cv;
    cv.u[0] = cvt_pk_bf16(fa.x, fa.y);
    cv.u[1] = cvt_pk_bf16(fa.z, fa.w);
    cv.u[2] = cvt_pk_bf16(fb.x, fb.y);
    cv.u[3] = cvt_pk_bf16(fb.z, fb.w);
    bx[kc] = cv.v;
  }

  // acc init = residual x (f32-exact): acc[mt][4q+j] = x[s=l31][d=32mt+8q+4g5+j]
  f32x16 acc[2];
  {
    const float* prow = xb + ((size_t)l31 << 6);
#pragma unroll
    for (int mt = 0; mt < 2; ++mt)
#pragma unroll
      for (int q = 0; q < 4; ++q) {
        float4 v =
            *reinterpret_cast<const float4*>(prow + mt * 32 + q * 8 + g5 * 4);
        acc[mt][4 * q + 0] = v.x;
        acc[mt][4 * q + 1] = v.y;
        acc[mt][4 * q + 2] = v.z;
        acc[mt][4 * q + 3] = v.w;
      }
  }

  __syncthreads();  // weight staging complete

  const char* lw1 = lds + lane * 16;
  const char* lw2 = lds + 32768 + lane * 16;

  const f32x16 vzero = {0.f, 0.f, 0.f, 0.f, 0.f, 0.f, 0.f, 0.f,
                        0.f, 0.f, 0.f, 0.f, 0.f, 0.f, 0.f, 0.f};

#pragma unroll
  for (int pr = 0; pr < 4; ++pr) {
    const int hcA = 2 * pr, hcB = 2 * pr + 1;

    // ---- GEMM1 for BOTH sub-chunks first (independent chains A,B) ----
    f32x16 ahA = vzero, ahB = vzero;
#pragma unroll
    for (int kc = 0; kc < 4; ++kc) {
      bf16x8 a1A = *reinterpret_cast<const bf16x8*>(lw1 + (hcA * 4 + kc) * 1024);
      ahA = __builtin_amdgcn_mfma_f32_32x32x16_bf16(a1A, bx[kc], ahA, 0, 0, 0);
      bf16x8 a1B = *reinterpret_cast<const bf16x8*>(lw1 + (hcB * 4 + kc) * 1024);
      ahB = __builtin_amdgcn_mfma_f32_32x32x16_bf16(a1B, bx[kc], ahB, 0, 0, 0);
    }

    // ---- silu + pack + permswap for both (two independent VALU streams) ----
    bf16x8 bhA[2], bhB[2];
#pragma unroll
    for (int c = 0; c < 2; ++c) {
      uint32_t A0 = silu2_pack(ahA[8 * c + 0], ahA[8 * c + 1]);
      uint32_t A1 = silu2_pack(ahA[8 * c + 2], ahA[8 * c + 3]);
      uint32_t B0 = silu2_pack(ahA[8 * c + 4], ahA[8 * c + 5]);
      uint32_t B1 = silu2_pack(ahA[8 * c + 6], ahA[8 * c + 7]);
      permswap(A0, B0);
      permswap(A1, B1);
      union { uint32_t u[4]; bf16x8 v; } f;
      f.u[0] = A0; f.u[1] = A1; f.u[2] = B0; f.u[3] = B1;
      bhA[c] = f.v;
    }
#pragma unroll
    for (int c = 0; c < 2; ++c) {
      uint32_t A0 = silu2_pack(ahB[8 * c + 0], ahB[8 * c + 1]);
      uint32_t A1 = silu2_pack(ahB[8 * c + 2], ahB[8 * c + 3]);
      uint32_t B0 = silu2_pack(ahB[8 * c + 4], ahB[8 * c + 5]);
      uint32_t B1 = silu2_pack(ahB[8 * c + 6], ahB[8 * c + 7]);
      permswap(A0, B0);
      permswap(A1, B1);
      union { uint32_t u[4]; bf16x8 v; } f;
      f.u[0] = A0; f.u[1] = A1; f.u[2] = B0; f.u[3] = B1;
      bhB[c] = f.v;
    }

    // ---- GEMM2 for both sub-chunks ----
#pragma unroll
    for (int c = 0; c < 2; ++c)
#pragma unroll
      for (int mt = 0; mt < 2; ++mt) {
        bf16x8 a2A = *reinterpret_cast<const bf16x8*>(
            lw2 + (hcA * 4 + mt * 2 + c) * 1024);
        acc[mt] = __builtin_amdgcn_mfma_f32_32x32x16_bf16(a2A, bhA[c], acc[mt],
                                                          0, 0, 0);
      }
#pragma unroll
    for (int c = 0; c < 2; ++c)
#pragma unroll
      for (int mt = 0; mt < 2; ++mt) {
        bf16x8 a2B = *reinterpret_cast<const bf16x8*>(
            lw2 + (hcB * 4 + mt * 2 + c) * 1024);
        acc[mt] = __builtin_amdgcn_mfma_f32_32x32x16_bf16(a2B, bhB[c], acc[mt],
                                                          0, 0, 0);
      }
  }

  // ---- epilogue: direct global stores ----
  float* prow = outg + (((size_t)b * SS + s_base + l31) << 6);
#pragma unroll
  for (int mt = 0; mt < 2; ++mt)
#pragma unroll
    for (int q = 0; q < 4; ++q) {
      float4 v;
      v.x = acc[mt][4 * q + 0];
      v.y = acc[mt][4 * q + 1];
      v.z = acc[mt][4 * q + 2];
      v.w = acc[mt][4 * q + 3];
      *reinterpret_cast<float4*>(prow + mt * 32 + q * 8 + g5 * 4) = v;
    }
}

extern "C" void kernel_launch(void* const* d_in, const int* in_sizes, int n_in,
                              void* d_out, int out_size, void* d_ws, size_t ws_size,
                              hipStream_t stream) {
  const float* x  = (const float*)d_in[0];
  const float* W1 = (const float*)d_in[1];
  const float* W2 = (const float*)d_in[2];
  float* out = (float*)d_out;

  ushort* W1f = (ushort*)d_ws;                       // bf16 frag-major, 4 MB
  ushort* W2f = W1f + (size_t)BB * DD * HH;          // bf16 frag-major, 4 MB

  transpose_w<<<2048, 256, 0, stream>>>(W1, W2, W1f, W2f);
  mlp_fused<<<2048, 512, 0, stream>>>(x, W1f, W2f, out);
}

// Round 14
// 79.037 us; speedup vs baseline: 1.6336x; 1.0757x over previous
//
#include <hip/hip_runtime.h>
#include <stdint.h>

#define BB 128
#define SS 4096
#define DD 64
#define HH 256

typedef short bf16x8 __attribute__((ext_vector_type(8)));
typedef float f32x16 __attribute__((ext_vector_type(16)));
typedef float f32x2 __attribute__((ext_vector_type(2)));

__device__ __forceinline__ uint32_t cvt_pk_bf16(float lo, float hi) {
  uint32_t r;
  asm("v_cvt_pk_bf16_f32 %0, %1, %2" : "=v"(r) : "v"(lo), "v"(hi));
  return r;
}

__device__ __forceinline__ float bflo(uint32_t w) {
  union { uint32_t u; float f; } c; c.u = w << 16; return c.f;
}
__device__ __forceinline__ float bfhi(uint32_t w) {
  union { uint32_t u; float f; } c; c.u = w & 0xffff0000u; return c.f;
}

// v_permlane32_swap_b32: new_a = [a.row0, b.row0], new_b = [a.row1, b.row1]
__device__ __forceinline__ void permswap(uint32_t& a, uint32_t& b) {
  asm("v_permlane32_swap_b32 %0, %1" : "+v"(a), "+v"(b));
}

// packed-f32 silu on a pair, returns packed bf16 word.
__device__ __forceinline__ uint32_t silu2_pack(float a, float b) {
  f32x2 v = {a, b};
  f32x2 m = v * (-1.44269504f);          // v_pk_mul_f32
  float ea, eb;
  asm("v_exp_f32 %0, %1" : "=v"(ea) : "v"(m.x));
  asm("v_exp_f32 %0, %1" : "=v"(eb) : "v"(m.y));
  f32x2 d = {ea, eb};
  d = d + (f32x2){1.0f, 1.0f};           // v_pk_add_f32
  f32x2 r = {__builtin_amdgcn_rcpf(d.x), __builtin_amdgcn_rcpf(d.y)};
  f32x2 o = v * r;                       // v_pk_mul_f32
  return cvt_pk_bf16(o.x, o.y);
}

__device__ __forceinline__ void gload16(const void* g, void* l) {
  __builtin_amdgcn_global_load_lds(
      (const __attribute__((address_space(1))) void*)g,
      (__attribute__((address_space(3))) void*)l, 16, 0, 0);
}

// -------- pre-pass: weights -> FRAGMENT-MAJOR bf16 layout in workspace -----
// W1f: per b, 32 tiles (hc*4+kc) of 64 lanes x 16B:
//   lane holds W1[d = kc*16+(lane>>5)*8 + j][h = hc*32+(lane&31)], j=0..7
// W2f: per b, 32 tiles (hc*4+mt*2+c) of 64 lanes x 16B:
//   lane holds W2[h = hc*32+c*16+(lane>>5)*8 + j][d = mt*32+(lane&31)]
__global__ __launch_bounds__(256) void transpose_w(
    const float* __restrict__ W1, const float* __restrict__ W2,
    ushort* __restrict__ W1f, ushort* __restrict__ W2f) {
  int g = blockIdx.x * 256 + threadIdx.x;
  const int half = (BB * DD * HH) / 8;  // 262144
  float v[8];
  if (g < half) {
    size_t e = (size_t)g * 8;            // ushort index: b|tile|lane|j
    int b = (int)(e >> 14);
    int rem = (int)(e & 16383);
    int tile = rem >> 9;                 // hc*4 + kc
    int lane6 = (rem >> 3) & 63;
    int hc = tile >> 2, kc = tile & 3;
    int h = hc * 32 + (lane6 & 31);
    int d0 = kc * 16 + (lane6 >> 5) * 8;
    const float* src = W1 + ((size_t)b << 14) + h;  // + d*256
#pragma unroll
    for (int j = 0; j < 8; ++j) v[j] = src[(size_t)(d0 + j) << 8];
    uint4 o;
    o.x = cvt_pk_bf16(v[0], v[1]); o.y = cvt_pk_bf16(v[2], v[3]);
    o.z = cvt_pk_bf16(v[4], v[5]); o.w = cvt_pk_bf16(v[6], v[7]);
    *reinterpret_cast<uint4*>(W1f + e) = o;
  } else if (g < 2 * half) {
    size_t e = (size_t)(g - half) * 8;
    int b = (int)(e >> 14);
    int rem = (int)(e & 16383);
    int tile = rem >> 9;                 // hc*4 + mt*2 + c
    int lane6 = (rem >> 3) & 63;
    int hc = tile >> 2, mt = (tile >> 1) & 1, c = tile & 1;
    int d = mt * 32 + (lane6 & 31);
    int h0 = hc * 32 + c * 16 + (lane6 >> 5) * 8;
    const float* src = W2 + ((size_t)b << 14) + d;  // + h*64
#pragma unroll
    for (int j = 0; j < 8; ++j) v[j] = src[(size_t)(h0 + j) << 6];
    uint4 o;
    o.x = cvt_pk_bf16(v[0], v[1]); o.y = cvt_pk_bf16(v[2], v[3]);
    o.z = cvt_pk_bf16(v[4], v[5]); o.w = cvt_pk_bf16(v[6], v[7]);
    *reinterpret_cast<uint4*>(W2f + e) = o;
  }
}

// ---------------- main fused kernel ----------------
// Block = 512 thr (8 waves), one b, 256 s-rows (wave = 32 rows).
// ALL global traffic coalesced (the r4-r13 kernels had 64-line scattered
// x reads + stores serializing the texture pipe ~40us/CU):
//   x: coalesced 32B/thread f32 reads -> bf16 LDS tile (time-shares the
//      W2f region before W2f is staged), frags + residual read from LDS.
//   out: f32 bounce through the (dead) weight LDS -> 1KB-contiguous stores.
// LDS 64 KB: [0,32K) W1f frag-major | [32K,64K) x-stage then W2f frag-major.
// Main loop (r8/r12 form): ds_read_b128 at lane*16+literal, 0 conflicts;
// silu2_pack (packed f32) + permlane32_swap in-register conversion.
__global__ __launch_bounds__(512, 4) void mlp_fused(
    const float* __restrict__ xg, const ushort* __restrict__ w1f,
    const ushort* __restrict__ w2f, float* __restrict__ outg) {
  __shared__ int4 lds4[65536 / 16];
  char* lds = (char*)lds4;

  const int tid = threadIdx.x;
  const int wave = tid >> 6;
  const int lane = tid & 63;
  const int l31 = lane & 31;
  const int g5 = lane >> 5;

  // 2048 blocks; XCD-aware swizzle: XCD k owns b in [16k, 16k+16)
  int raw = blockIdx.x;
  int logical = (raw & 7) * 256 + (raw >> 3);
  const int b = logical >> 4;            // 16 blocks per b
  const int st = logical & 15;
  const int s_base = st * 256 + wave * 32;

  const char* w1b = (const char*)(w1f + ((size_t)b << 14));
  const char* w2b = (const char*)(w2f + ((size_t)b << 14));
  char* xlds = lds + 32768;

  // (1) issue W1f staging into region A (async, linear copy)
#pragma unroll
  for (int r = 0; r < 4; ++r) {
    uint32_t o = (uint32_t)(r * 8192 + tid * 16);
    gload16(w1b + o, lds + o);
  }

  // (2) stage x tile (256 rows x 64 d) f32->bf16 into region B, COALESCED:
  // thread reads 32B contiguous; LDS rows 128B, swizzle ^((row&7)<<4)
  const float* xblk = xg + (((size_t)b * SS + st * 256) << 6);
#pragma unroll
  for (int ps = 0; ps < 4; ++ps) {
    int e = ps * 4096 + tid * 8;
    float4 fa = *reinterpret_cast<const float4*>(xblk + e);
    float4 fb = *reinterpret_cast<const float4*>(xblk + e + 4);
    uint4 pk;
    pk.x = cvt_pk_bf16(fa.x, fa.y);
    pk.y = cvt_pk_bf16(fa.z, fa.w);
    pk.z = cvt_pk_bf16(fb.x, fb.y);
    pk.w = cvt_pk_bf16(fb.z, fb.w);
    int row = e >> 6, d0 = e & 63;
    uint32_t byte = (uint32_t)(row * 128 + d0 * 2);
    byte ^= (uint32_t)(row & 7) << 4;
    *reinterpret_cast<uint4*>(xlds + byte) = pk;
  }

  __syncthreads();  // x tile in LDS (W1f also drained, harmless)

  // (3) frags + residual from LDS (wave-local rows R = 32*wave + l31)
  const int R = wave * 32 + l31;
  const uint32_t rs = (uint32_t)(R & 7) << 4;

  bf16x8 bx[4];
#pragma unroll
  for (int kc = 0; kc < 4; ++kc) {
    uint32_t byte = (uint32_t)(R * 128 + kc * 32 + g5 * 16) ^ rs;
    bx[kc] = *reinterpret_cast<const bf16x8*>(xlds + byte);
  }

  f32x16 acc[2];  // residual init (bf16-rounded; error budget OK per r2)
#pragma unroll
  for (int mt = 0; mt < 2; ++mt)
#pragma unroll
    for (int q = 0; q < 4; ++q) {
      uint32_t byte = (uint32_t)(R * 128 + mt * 64 + q * 16 + g5 * 8) ^ rs;
      uint2 w = *reinterpret_cast<const uint2*>(xlds + byte);
      acc[mt][4 * q + 0] = bflo(w.x);
      acc[mt][4 * q + 1] = bfhi(w.x);
      acc[mt][4 * q + 2] = bflo(w.y);
      acc[mt][4 * q + 3] = bfhi(w.y);
    }

  __syncthreads();  // all reads of x-stage done; region B reusable

  // (4) stage W2f into region B (linear async copy)
#pragma unroll
  for (int r = 0; r < 4; ++r) {
    uint32_t o = (uint32_t)(r * 8192 + tid * 16);
    gload16(w2b + o, xlds + o);
  }

  __syncthreads();  // W2f ready

  const char* lw1 = lds + lane * 16;
  const char* lw2 = xlds + lane * 16;

  const f32x16 vzero = {0.f, 0.f, 0.f, 0.f, 0.f, 0.f, 0.f, 0.f,
                        0.f, 0.f, 0.f, 0.f, 0.f, 0.f, 0.f, 0.f};

#pragma unroll
  for (int hc = 0; hc < 8; ++hc) {
    // ---- GEMM1 (swapped, 32h x 32s) ----
    f32x16 ah = vzero;
#pragma unroll
    for (int kc = 0; kc < 4; ++kc) {
      bf16x8 a1 = *reinterpret_cast<const bf16x8*>(lw1 + (hc * 4 + kc) * 1024);
      ah = __builtin_amdgcn_mfma_f32_32x32x16_bf16(a1, bx[kc], ah, 0, 0, 0);
    }

    // ---- silu (packed) + pack + permlane32_swap -> GEMM2 B-frags ----
    bf16x8 bh[2];
#pragma unroll
    for (int c = 0; c < 2; ++c) {
      uint32_t A0 = silu2_pack(ah[8 * c + 0], ah[8 * c + 1]);
      uint32_t A1 = silu2_pack(ah[8 * c + 2], ah[8 * c + 3]);
      uint32_t B0 = silu2_pack(ah[8 * c + 4], ah[8 * c + 5]);
      uint32_t B1 = silu2_pack(ah[8 * c + 6], ah[8 * c + 7]);
      permswap(A0, B0);
      permswap(A1, B1);
      union { uint32_t u[4]; bf16x8 v; } f;
      f.u[0] = A0; f.u[1] = A1; f.u[2] = B0; f.u[3] = B1;
      bh[c] = f.v;
    }

    // ---- GEMM2 (swapped) ----
#pragma unroll
    for (int c = 0; c < 2; ++c)
#pragma unroll
      for (int mt = 0; mt < 2; ++mt) {
        bf16x8 a2 = *reinterpret_cast<const bf16x8*>(
            lw2 + (hc * 4 + mt * 2 + c) * 1024);
        acc[mt] =
            __builtin_amdgcn_mfma_f32_32x32x16_bf16(a2, bh[c], acc[mt], 0, 0, 0);
      }
  }

  __syncthreads();  // weight LDS dead; reuse all 64 KB for out bounce

  // (5) epilogue: f32 out tile -> per-wave 8 KB LDS slice -> coalesced store
  char* slice = lds + wave * 8192;  // 32 rows x 256 B
  {
    uint32_t sw = (uint32_t)(l31 & 7) << 4;
#pragma unroll
    for (int mt = 0; mt < 2; ++mt)
#pragma unroll
      for (int q = 0; q < 4; ++q) {
        uint32_t byte =
            ((uint32_t)(l31 * 256 + mt * 128 + q * 32 + g5 * 16)) ^ sw;
        float4 v;
        v.x = acc[mt][4 * q + 0];
        v.y = acc[mt][4 * q + 1];
        v.z = acc[mt][4 * q + 2];
        v.w = acc[mt][4 * q + 3];
        *reinterpret_cast<float4*>(slice + byte) = v;
      }
  }
  __builtin_amdgcn_sched_barrier(0);
  {
    float* orow = outg + (((size_t)b * SS + s_base) << 6);
#pragma unroll
    for (int it = 0; it < 8; ++it) {
      uint32_t o = (uint32_t)(it * 1024 + lane * 16);
      uint32_t row = o >> 8;
      uint32_t byte = o ^ ((row & 7) << 4);
      float4 v = *reinterpret_cast<const float4*>(slice + byte);
      *reinterpret_cast<float4*>(orow + ((size_t)row << 6) + ((o & 255) >> 2)) =
          v;
    }
  }
}

extern "C" void kernel_launch(void* const* d_in, const int* in_sizes, int n_in,
                              void* d_out, int out_size, void* d_ws, size_t ws_size,
                              hipStream_t stream) {
  const float* x  = (const float*)d_in[0];
  const float* W1 = (const float*)d_in[1];
  const float* W2 = (const float*)d_in[2];
  float* out = (float*)d_out;

  ushort* W1f = (ushort*)d_ws;                       // bf16 frag-major, 4 MB
  ushort* W2f = W1f + (size_t)BB * DD * HH;          // bf16 frag-major, 4 MB

  transpose_w<<<2048, 256, 0, stream>>>(W1, W2, W1f, W2f);
  mlp_fused<<<2048, 512, 0, stream>>>(x, W1f, W2f, out);
}